// Round 4
// baseline (167.813 us; speedup 1.0000x reference)
//
#include <hip/hip_runtime.h>

#define FH 50
#define FW 75
#define FC 512
#define NPOOL 7

typedef float f32x4 __attribute__((ext_vector_type(4)));

__global__ __launch_bounds__(128) void roi_pool_kernel(
    const float* __restrict__ fmap,     // (1, FH, FW, FC)
    const float* __restrict__ rois,     // (N, 4) = x1,y1,x2,y2 in image coords
    const int*   __restrict__ img_size, // [800, 1200]
    float* __restrict__ out,            // (N, 7, 7, FC)
    int N)
{
    const int bid = blockIdx.x;
    const int n  = bid / (NPOOL * NPOOL);
    const int p  = bid % (NPOOL * NPOOL);
    const int py = p / NPOOL;
    const int px = p % NPOOL;
    if (n >= N) return;

    const float img_h = (float)(img_size[0] - 1);
    const float img_w = (float)(img_size[1] - 1);

    const float rx1 = rois[n * 4 + 0];
    const float ry1 = rois[n * 4 + 1];
    const float rx2 = rois[n * 4 + 2];
    const float ry2 = rois[n * 4 + 3];
    const float by1 = ry1 / img_h;
    const float bx1 = rx1 / img_w;
    const float by2 = ry2 / img_h;
    const float bx2 = rx2 / img_w;

    const float fh = (float)(FH - 1);   // 49
    const float fw = (float)(FW - 1);   // 74
    const float stepy = (by2 - by1) * fh * (1.0f / 13.0f);
    const float stepx = (bx2 - bx1) * fw * (1.0f / 13.0f);
    const float basey = by1 * fh;
    const float basex = bx1 * fw;

    const int t  = threadIdx.x;
    const int c4 = t * 4;   // 128 threads * 4 channels = 512

    // ---- Phase 1: coordinate math (block-uniform) ----
    int   off00[4], off01[4], off10[4], off11[4];
    float wy_[4], wx_[4];
    bool  valid_[4];
    #pragma unroll
    for (int kk = 0; kk < 4; ++kk) {
        const int iy = py * 2 + (kk >> 1);
        const int ix = px * 2 + (kk & 1);
        const float ys = basey + (float)iy * stepy;
        const float xs = basex + (float)ix * stepx;
        valid_[kk] = (ys >= 0.0f) & (ys <= fh) & (xs >= 0.0f) & (xs <= fw);

        const float y0f = floorf(ys);
        const float x0f = floorf(xs);
        wy_[kk] = ys - y0f;
        wx_[kk] = xs - x0f;
        int y0i = (int)y0f; y0i = min(max(y0i, 0), FH - 1);
        int x0i = (int)x0f; x0i = min(max(x0i, 0), FW - 1);
        const int y1i = min(y0i + 1, FH - 1);
        const int x1i = min(x0i + 1, FW - 1);
        // Hoist block-uniform offsets to SGPRs -> saddr-form loads.
        off00[kk] = __builtin_amdgcn_readfirstlane((y0i * FW + x0i) * FC);
        off01[kk] = __builtin_amdgcn_readfirstlane((y0i * FW + x1i) * FC);
        off10[kk] = __builtin_amdgcn_readfirstlane((y1i * FW + x0i) * FC);
        off11[kk] = __builtin_amdgcn_readfirstlane((y1i * FW + x1i) * FC);
    }

    // ---- Phase 2: issue ALL 16 loads before any use (max MLP) ----
    f32x4 tl0, tr0, bl0, br0, tl1, tr1, bl1, br1;
    f32x4 tl2, tr2, bl2, br2, tl3, tr3, bl3, br3;
    tl0 = *(const f32x4*)(fmap + off00[0] + c4);
    tr0 = *(const f32x4*)(fmap + off01[0] + c4);
    bl0 = *(const f32x4*)(fmap + off10[0] + c4);
    br0 = *(const f32x4*)(fmap + off11[0] + c4);
    tl1 = *(const f32x4*)(fmap + off00[1] + c4);
    tr1 = *(const f32x4*)(fmap + off01[1] + c4);
    bl1 = *(const f32x4*)(fmap + off10[1] + c4);
    br1 = *(const f32x4*)(fmap + off11[1] + c4);
    tl2 = *(const f32x4*)(fmap + off00[2] + c4);
    tr2 = *(const f32x4*)(fmap + off01[2] + c4);
    bl2 = *(const f32x4*)(fmap + off10[2] + c4);
    br2 = *(const f32x4*)(fmap + off11[2] + c4);
    tl3 = *(const f32x4*)(fmap + off00[3] + c4);
    tr3 = *(const f32x4*)(fmap + off01[3] + c4);
    bl3 = *(const f32x4*)(fmap + off10[3] + c4);
    br3 = *(const f32x4*)(fmap + off11[3] + c4);

    // Loads cannot sink below a memory clobber: forces all 16 in flight.
    asm volatile("" ::: "memory");

    // ---- Phase 3: interpolate + max ----
    f32x4 m = (f32x4){-INFINITY, -INFINITY, -INFINITY, -INFINITY};

    #define BILERP_MAX(TL, TR, BL, BR, K)                                   \
    {                                                                        \
        const float wy = wy_[K], wx = wx_[K];                                \
        f32x4 top = TL + wx * (TR - TL);                                     \
        f32x4 bot = BL + wx * (BR - BL);                                     \
        f32x4 v = top + wy * (bot - top);                                    \
        if (!valid_[K]) v = (f32x4){0.0f, 0.0f, 0.0f, 0.0f};                 \
        m.x = fmaxf(m.x, v.x);                                               \
        m.y = fmaxf(m.y, v.y);                                               \
        m.z = fmaxf(m.z, v.z);                                               \
        m.w = fmaxf(m.w, v.w);                                               \
    }

    BILERP_MAX(tl0, tr0, bl0, br0, 0)
    BILERP_MAX(tl1, tr1, bl1, br1, 1)
    BILERP_MAX(tl2, tr2, bl2, br2, 2)
    BILERP_MAX(tl3, tr3, bl3, br3, 3)
    #undef BILERP_MAX

    // ---- Nontemporal store: output is write-once, never re-read ----
    f32x4* dst = (f32x4*)(out + (((long)n * NPOOL + py) * NPOOL + px) * FC + c4);
    __builtin_nontemporal_store(m, dst);
}

extern "C" void kernel_launch(void* const* d_in, const int* in_sizes, int n_in,
                              void* d_out, int out_size, void* d_ws, size_t ws_size,
                              hipStream_t stream) {
    const float* fmap     = (const float*)d_in[0];
    const float* rois     = (const float*)d_in[1];
    const int*   img_size = (const int*)d_in[2];
    float* out = (float*)d_out;

    const int N = in_sizes[1] / 4;   // rois is (N,4)
    const int blocks = N * NPOOL * NPOOL;
    roi_pool_kernel<<<blocks, 128, 0, stream>>>(fmap, rois, img_size, out, N);
}

// Round 5
// 157.958 us; speedup vs baseline: 1.0624x; 1.0624x over previous
//
#include <hip/hip_runtime.h>

#define FH 50
#define FW 75
#define FC 512
#define NPOOL 7
#define NXCD 8

typedef float f32x4 __attribute__((ext_vector_type(4)));

__global__ __launch_bounds__(128) void roi_pool_kernel(
    const float* __restrict__ fmap,     // (1, FH, FW, FC)
    const float* __restrict__ rois,     // (N, 4) = x1,y1,x2,y2 in image coords
    const int*   __restrict__ img_size, // [800, 1200]
    float* __restrict__ out,            // (N, 7, 7, FC)
    int N)
{
    // ---- XCD-chunked bijective swizzle (T1): one ROI's 49 blocks -> one XCD ----
    const int nwg = gridDim.x;
    const int q = nwg / NXCD, r = nwg % NXCD;
    const int xcd = blockIdx.x % NXCD, local = blockIdx.x / NXCD;
    const int w = (xcd < r ? xcd * (q + 1) : r * (q + 1) + (xcd - r) * q) + local;

    const int n  = w / (NPOOL * NPOOL);
    const int p  = w % (NPOOL * NPOOL);
    const int py = p / NPOOL;
    const int px = p % NPOOL;
    if (n >= N) return;

    const float img_h = (float)(img_size[0] - 1);
    const float img_w = (float)(img_size[1] - 1);

    const float rx1 = rois[n * 4 + 0];
    const float ry1 = rois[n * 4 + 1];
    const float rx2 = rois[n * 4 + 2];
    const float ry2 = rois[n * 4 + 3];
    const float by1 = ry1 / img_h;
    const float bx1 = rx1 / img_w;
    const float by2 = ry2 / img_h;
    const float bx2 = rx2 / img_w;

    const float fh = (float)(FH - 1);   // 49
    const float fw = (float)(FW - 1);   // 74
    const float stepy = (by2 - by1) * fh * (1.0f / 13.0f);
    const float stepx = (bx2 - bx1) * fw * (1.0f / 13.0f);
    const float basey = by1 * fh;
    const float basex = bx1 * fw;

    const int t  = threadIdx.x;
    const int c4 = t * 4;   // 128 threads * 4 channels = 512

    // ---- Phase 1: coordinate math (block-uniform, hoisted to SGPR) ----
    int   off00[4], off01[4], off10[4], off11[4];
    float wy_[4], wx_[4];
    bool  valid_[4];
    #pragma unroll
    for (int kk = 0; kk < 4; ++kk) {
        const int iy = py * 2 + (kk >> 1);
        const int ix = px * 2 + (kk & 1);
        const float ys = basey + (float)iy * stepy;
        const float xs = basex + (float)ix * stepx;
        valid_[kk] = (ys >= 0.0f) & (ys <= fh) & (xs >= 0.0f) & (xs <= fw);

        const float y0f = floorf(ys);
        const float x0f = floorf(xs);
        wy_[kk] = ys - y0f;
        wx_[kk] = xs - x0f;
        int y0i = (int)y0f; y0i = min(max(y0i, 0), FH - 1);
        int x0i = (int)x0f; x0i = min(max(x0i, 0), FW - 1);
        const int y1i = min(y0i + 1, FH - 1);
        const int x1i = min(x0i + 1, FW - 1);
        off00[kk] = __builtin_amdgcn_readfirstlane((y0i * FW + x0i) * FC);
        off01[kk] = __builtin_amdgcn_readfirstlane((y0i * FW + x1i) * FC);
        off10[kk] = __builtin_amdgcn_readfirstlane((y1i * FW + x0i) * FC);
        off11[kk] = __builtin_amdgcn_readfirstlane((y1i * FW + x1i) * FC);
    }

    // ---- Phase 2: issue ALL 16 loads, then pin ALL results live in VGPRs ----
    f32x4 tl0, tr0, bl0, br0, tl1, tr1, bl1, br1;
    f32x4 tl2, tr2, bl2, br2, tl3, tr3, bl3, br3;
    tl0 = *(const f32x4*)(fmap + off00[0] + c4);
    tr0 = *(const f32x4*)(fmap + off01[0] + c4);
    bl0 = *(const f32x4*)(fmap + off10[0] + c4);
    br0 = *(const f32x4*)(fmap + off11[0] + c4);
    tl1 = *(const f32x4*)(fmap + off00[1] + c4);
    tr1 = *(const f32x4*)(fmap + off01[1] + c4);
    bl1 = *(const f32x4*)(fmap + off10[1] + c4);
    br1 = *(const f32x4*)(fmap + off11[1] + c4);
    tl2 = *(const f32x4*)(fmap + off00[2] + c4);
    tr2 = *(const f32x4*)(fmap + off01[2] + c4);
    bl2 = *(const f32x4*)(fmap + off10[2] + c4);
    br2 = *(const f32x4*)(fmap + off11[2] + c4);
    tl3 = *(const f32x4*)(fmap + off00[3] + c4);
    tr3 = *(const f32x4*)(fmap + off01[3] + c4);
    bl3 = *(const f32x4*)(fmap + off10[3] + c4);
    br3 = *(const f32x4*)(fmap + off11[3] + c4);

    // All 16 values are asm operands: they must ALL be materialized in
    // registers here, so no compute can be interleaved between the loads
    // and no load can be deferred. (A plain "memory" clobber does NOT
    // order the FP arithmetic -- learned R4.)
    asm volatile("" : "+v"(tl0), "+v"(tr0), "+v"(bl0), "+v"(br0),
                      "+v"(tl1), "+v"(tr1), "+v"(bl1), "+v"(br1),
                      "+v"(tl2), "+v"(tr2), "+v"(bl2), "+v"(br2),
                      "+v"(tl3), "+v"(tr3), "+v"(bl3), "+v"(br3));

    // ---- Phase 3: interpolate + max ----
    f32x4 m = (f32x4){-INFINITY, -INFINITY, -INFINITY, -INFINITY};

    #define BILERP_MAX(TL, TR, BL, BR, K)                                   \
    {                                                                        \
        const float wy = wy_[K], wx = wx_[K];                                \
        f32x4 top = TL + wx * (TR - TL);                                     \
        f32x4 bot = BL + wx * (BR - BL);                                     \
        f32x4 v = top + wy * (bot - top);                                    \
        if (!valid_[K]) v = (f32x4){0.0f, 0.0f, 0.0f, 0.0f};                 \
        m.x = fmaxf(m.x, v.x);                                               \
        m.y = fmaxf(m.y, v.y);                                               \
        m.z = fmaxf(m.z, v.z);                                               \
        m.w = fmaxf(m.w, v.w);                                               \
    }

    BILERP_MAX(tl0, tr0, bl0, br0, 0)
    BILERP_MAX(tl1, tr1, bl1, br1, 1)
    BILERP_MAX(tl2, tr2, bl2, br2, 2)
    BILERP_MAX(tl3, tr3, bl3, br3, 3)
    #undef BILERP_MAX

    // ---- Nontemporal store: output is write-once, never re-read ----
    f32x4* dst = (f32x4*)(out + (((long)n * NPOOL + py) * NPOOL + px) * FC + c4);
    __builtin_nontemporal_store(m, dst);
}

extern "C" void kernel_launch(void* const* d_in, const int* in_sizes, int n_in,
                              void* d_out, int out_size, void* d_ws, size_t ws_size,
                              hipStream_t stream) {
    const float* fmap     = (const float*)d_in[0];
    const float* rois     = (const float*)d_in[1];
    const int*   img_size = (const int*)d_in[2];
    float* out = (float*)d_out;

    const int N = in_sizes[1] / 4;   // rois is (N,4)
    const int blocks = N * NPOOL * NPOOL;
    roi_pool_kernel<<<blocks, 128, 0, stream>>>(fmap, rois, img_size, out, N);
}